// Round 2
// baseline (249.654 us; speedup 1.0000x reference)
//
#include <hip/hip_runtime.h>
#include <hip/hip_bf16.h>
#include <stdint.h>

// Problem constants (static graph layout)
#define NB 64
#define NN 4096
#define NS 512
#define NC 128
#define NTOTAL (NB*NN)          // 262144
#define NE 4194304
#define KSENT 3
#define KOTHER 1792
#define KPG (KSENT+KOTHER)      // 1795
#define NP (NB*KPG)             // 114880
#define NSENT_TOT (NB*KSENT)    // 192
#define NOTHER (NN-NS)          // 3584

// d_out element offsets (f32 elements), concatenated flat in return order:
// x_out[114880,128], edge_index_new[2,E], batch_out[P], perm[P], score[P], num_edges[1]
#define OFF_X     0ull
#define OFF_EDGE  14704640ull
#define OFF_BATCH 23093248ull
#define OFF_PERM  23208128ull
#define OFF_SCORE 23323008ull
#define OFF_NE    23437888ull

// Module-scope scratch. ~2.5 MB total.
__device__ float g_scores[NTOTAL];
__device__ int   g_perm[NP];
__device__ int   g_nodemap[NTOTAL];
__device__ int   g_cnt[512];
__device__ int   g_off[512];
__device__ float g_norm;

// f32 -> bf16 RNE, returned as f32 (upper 16 bits kept). Ref is bf16-rounded,
// so storing bf16-rounded f32 gives absmax 0 where the pipeline matches.
__device__ __forceinline__ float bfr(float f){
  uint32_t u = __float_as_uint(f);
  uint32_t r = u + 0x7FFFu + ((u >> 16) & 1u);
  return __uint_as_float(r & 0xFFFF0000u);
}

// Bit-exact replication of XLA:CPU EmitTanh (f32):
// clamp to +/-7.90531110763549805, rational P/Q (7/4 coeffs), separate
// mul+add (no contraction), |x|<0.0004 -> x passthrough.
__device__ __forceinline__ float xla_tanhf(float x){
#pragma clang fp contract(off)
  float xc = fminf(fmaxf(x, -7.90531110763549805f), 7.90531110763549805f);
  float x2 = __fmul_rn(xc, xc);
  float p = -2.76076847742355e-16f;
  p = __fadd_rn(__fmul_rn(p, x2),  2.00018790482477e-13f);
  p = __fadd_rn(__fmul_rn(p, x2), -8.60467152213735e-11f);
  p = __fadd_rn(__fmul_rn(p, x2),  5.12229709037114e-08f);
  p = __fadd_rn(__fmul_rn(p, x2),  1.48572235717979e-05f);
  p = __fadd_rn(__fmul_rn(p, x2),  6.37261928875436e-04f);
  p = __fadd_rn(__fmul_rn(p, x2),  4.89352455891786e-03f);
  p = __fmul_rn(xc, p);
  float q = 1.19825839466702e-06f;
  q = __fadd_rn(__fmul_rn(q, x2), 1.18534705686654e-04f);
  q = __fadd_rn(__fmul_rn(q, x2), 2.26843463243900e-03f);
  q = __fadd_rn(__fmul_rn(q, x2), 4.89352518554385e-03f);
  float r = __fdiv_rn(p, q);
  return (fabsf(x) < 0.0004f) ? x : r;
}

// ||w||: XLA vectorized reduce model — 16 mod-16 lanes, separate mul+add,
// shuffle-halving tree, then correctly-rounded sqrt.
__global__ void k_norm(const float* __restrict__ w){
#pragma clang fp contract(off)
  float l[16];
  for (int j = 0; j < 16; ++j) l[j] = 0.f;
  for (int k = 0; k < NC; k += 16)
    for (int j = 0; j < 16; ++j)
      l[j] = __fadd_rn(l[j], __fmul_rn(w[k+j], w[k+j]));
  for (int j = 0; j < 8; ++j) l[j] = __fadd_rn(l[j], l[j+8]);
  for (int j = 0; j < 4; ++j) l[j] = __fadd_rn(l[j], l[j+4]);
  for (int j = 0; j < 2; ++j) l[j] = __fadd_rn(l[j], l[j+2]);
  g_norm = __fsqrt_rn(__fadd_rn(l[0], l[1]));
}

// score_i = xla_tanh( fdiv( dot(x_i, w), norm ) )
// Dot models XLA:CPU RowMajorMatrixVectorProductEmitter at AVX-512 width:
// ONE 16-lane vector accumulator per row, k step 16, unfused mul+add
// (VSL::MulAdd), then AddReduce shuffle-halving tree 16->8->4->2->1.
__global__ __launch_bounds__(256) void k_scores(const float* __restrict__ x,
                                                const float* __restrict__ w){
#pragma clang fp contract(off)
  __shared__ float ws[NC];
  if (threadIdx.x < NC) ws[threadIdx.x] = w[threadIdx.x];
  __syncthreads();
  int i = blockIdx.x*256 + threadIdx.x;
  const float* row = x + (size_t)i*NC;
  float l[16];
#pragma unroll
  for (int j = 0; j < 16; ++j) l[j] = 0.f;
#pragma unroll
  for (int k = 0; k < NC; k += 16){
#pragma unroll
    for (int j = 0; j < 16; ++j)
      l[j] = __fadd_rn(l[j], __fmul_rn(row[k+j], ws[k+j]));
  }
#pragma unroll
  for (int j = 0; j < 8; ++j) l[j] = __fadd_rn(l[j], l[j+8]);
#pragma unroll
  for (int j = 0; j < 4; ++j) l[j] = __fadd_rn(l[j], l[j+4]);
#pragma unroll
  for (int j = 0; j < 2; ++j) l[j] = __fadd_rn(l[j], l[j+2]);
  float acc = __fadd_rn(l[0], l[1]);
  float t = __fdiv_rn(acc, g_norm);
  g_scores[i] = xla_tanhf(t);
}

// Sort key: ascending u64 order == (score descending, index ascending)
// == XLA TopK comparator (values equal -> lower index first).
__device__ __forceinline__ unsigned long long skey(float s, int idx){
  uint32_t u = __float_as_uint(s);
  u = (u & 0x80000000u) ? ~u : (u | 0x80000000u); // monotone f32->u32
  u = ~u;                                          // descending
  return ((unsigned long long)u << 32) | (uint32_t)idx;
}

__device__ void bitonic(unsigned long long* sh, int n, int tid, int nt){
  for (int k = 2; k <= n; k <<= 1){
    for (int j = k >> 1; j > 0; j >>= 1){
      __syncthreads();
      for (int i = tid; i < n; i += nt){
        int l = i ^ j;
        if (l > i){
          unsigned long long a = sh[i], b = sh[l];
          bool up = ((i & k) == 0);
          if ((a > b) == up){ sh[i] = b; sh[l] = a; }
        }
      }
    }
  }
  __syncthreads();
}

// One block per graph: sort 512 sentence keys (take 3), sort 3584 other keys
// padded to 4096 (take 1792). Writes int perm in reference order.
__global__ __launch_bounds__(512) void k_topk(){
  __shared__ unsigned long long keys[4096];
  int g = blockIdx.x, tid = threadIdx.x;
  const float* sg = g_scores + g*NN;
  if (tid < NS) keys[tid] = skey(sg[tid], tid);
  __syncthreads();
  bitonic(keys, NS, tid, 512);
  if (tid < KSENT) g_perm[g*KSENT + tid] = g*NN + (int)(keys[tid] & 0xFFFFFFFFu);
  __syncthreads();
  for (int i = tid; i < 4096; i += 512)
    keys[i] = (i < NOTHER) ? skey(sg[NS + i], i) : 0xFFFFFFFFFFFFFFFFull;
  __syncthreads();
  bitonic(keys, 4096, tid, 512);
  for (int j = tid; j < KOTHER; j += 512)
    g_perm[NSENT_TOT + g*KOTHER + j] = g*NN + NS + (int)(keys[j] & 0xFFFFFFFFu);
}

__global__ void k_nm_init(){
  int i = blockIdx.x*blockDim.x + threadIdx.x;
  g_nodemap[i] = -1;
}
__global__ void k_nm_set(){
  int p = blockIdx.x*blockDim.x + threadIdx.x;
  if (p < NP) g_nodemap[g_perm[p]] = p;
}

// Pre-fill whole edge output region with -1.0f (bf16(-1) == -1.0).
__global__ void k_fill(float* __restrict__ out){
  size_t i = (size_t)blockIdx.x*blockDim.x + threadIdx.x;
  float4 v; v.x = v.y = v.z = v.w = -1.0f;
  ((float4*)(out + OFF_EDGE))[i] = v;
}

// Per-block (8192 edges) kept-edge count.
__global__ __launch_bounds__(256) void k_count(const int* __restrict__ ei){
  int base = blockIdx.x * 8192;
  int c = 0;
  for (int s = 0; s < 8192; s += 256){
    int e = base + s + threadIdx.x;
    c += (g_nodemap[ei[e]] >= 0) && (g_nodemap[ei[NE + e]] >= 0);
  }
  __shared__ int red[256];
  red[threadIdx.x] = c; __syncthreads();
  for (int st = 128; st > 0; st >>= 1){
    if (threadIdx.x < st) red[threadIdx.x] += red[threadIdx.x + st];
    __syncthreads();
  }
  if (threadIdx.x == 0) g_cnt[blockIdx.x] = red[0];
}

// Exclusive scan of 512 block counts + emit num_edges.
__global__ void k_scan(float* __restrict__ out){
  int acc = 0;
  for (int i = 0; i < 512; ++i){ g_off[i] = acc; acc += g_cnt[i]; }
  out[OFF_NE] = bfr((float)acc);
}

// Stable compaction scatter: kept edges (remapped ids) to the front, original order.
__global__ __launch_bounds__(256) void k_scatter(const int* __restrict__ ei,
                                                 float* __restrict__ out){
  __shared__ int wsum[4];
  int base = blockIdx.x * 8192;
  int running = g_off[blockIdx.x];
  int lane = threadIdx.x & 63, wid = threadIdx.x >> 6;
  for (int s = 0; s < 8192; s += 256){
    int e = base + s + threadIdx.x;
    int r = g_nodemap[ei[e]], c = g_nodemap[ei[NE + e]];
    bool keep = (r >= 0) && (c >= 0);
    unsigned long long m = __ballot(keep);
    if (lane == 0) wsum[wid] = __popcll(m);
    __syncthreads();
    int wbase = 0;
    #pragma unroll
    for (int w2 = 0; w2 < 4; ++w2) if (w2 < wid) wbase += wsum[w2];
    int tot = wsum[0] + wsum[1] + wsum[2] + wsum[3];
    if (keep){
      int pos = running + wbase + __popcll(m & ((1ull << lane) - 1ull));
      out[OFF_EDGE + pos]      = bfr((float)r);
      out[OFF_EDGE + NE + pos] = bfr((float)c);
    }
    running += tot;
    __syncthreads();   // protect wsum from next iteration's overwrite (race fix)
  }
}

// x_out = x[perm]*score[perm] (f32, bf16-rounded), plus batch/perm/score outputs.
__global__ __launch_bounds__(256) void k_gather(const float* __restrict__ x,
                                                float* __restrict__ out){
  size_t idx = (size_t)blockIdx.x*256 + threadIdx.x;
  int p    = (int)(idx >> 7);
  int ccol = (int)(idx & 127);
  int node = g_perm[p];
  float s = g_scores[node];
  float v = __fmul_rn(x[(size_t)node*NC + ccol], s);
  out[OFF_X + idx] = bfr(v);
  if (ccol == 0){
    out[OFF_BATCH + p] = bfr((float)(node >> 12)); // node / N
    out[OFF_PERM  + p] = bfr((float)node);
    out[OFF_SCORE + p] = bfr(s);
  }
}

extern "C" void kernel_launch(void* const* d_in, const int* in_sizes, int n_in,
                              void* d_out, int out_size, void* d_ws, size_t ws_size,
                              hipStream_t stream) {
  const float* x = (const float*)d_in[0];
  const float* w = (const float*)d_in[1];
  const int*   ei = (const int*)d_in[2];
  float* out = (float*)d_out;

  hipLaunchKernelGGL(k_norm,    dim3(1),            dim3(1),   0, stream, w);
  hipLaunchKernelGGL(k_scores,  dim3(NTOTAL/256),   dim3(256), 0, stream, x, w);
  hipLaunchKernelGGL(k_topk,    dim3(NB),           dim3(512), 0, stream);
  hipLaunchKernelGGL(k_nm_init, dim3(NTOTAL/256),   dim3(256), 0, stream);
  hipLaunchKernelGGL(k_nm_set,  dim3((NP+255)/256), dim3(256), 0, stream);
  hipLaunchKernelGGL(k_fill,    dim3(8192),         dim3(256), 0, stream, out);
  hipLaunchKernelGGL(k_count,   dim3(512),          dim3(256), 0, stream, ei);
  hipLaunchKernelGGL(k_scan,    dim3(1),            dim3(1),   0, stream, out);
  hipLaunchKernelGGL(k_scatter, dim3(512),          dim3(256), 0, stream, ei, out);
  hipLaunchKernelGGL(k_gather,  dim3((NP*NC)/256),  dim3(256), 0, stream, x, out);
}

// Round 3
// 157.466 us; speedup vs baseline: 1.5854x; 1.5854x over previous
//
#include <hip/hip_runtime.h>
#include <hip/hip_bf16.h>
#include <stdint.h>

// Problem constants (static graph layout)
#define NB 64
#define NN 4096
#define NS 512
#define NC 128
#define NTOTAL (NB*NN)          // 262144
#define NE 4194304
#define KSENT 3
#define KOTHER 1792
#define KPG (KSENT+KOTHER)      // 1795
#define NP (NB*KPG)             // 114880
#define NSENT_TOT (NB*KSENT)    // 192
#define NOTHER (NN-NS)          // 3584

// d_out element offsets (f32 elements), concatenated flat in return order:
// x_out[114880,128], edge_index_new[2,E], batch_out[P], perm[P], score[P], num_edges[1]
#define OFF_X     0ull
#define OFF_EDGE  14704640ull
#define OFF_BATCH 23093248ull
#define OFF_PERM  23208128ull
#define OFF_SCORE 23323008ull
#define OFF_NE    23437888ull

// Module-scope scratch. ~2.5 MB total.
__device__ float g_scores[NTOTAL];
__device__ int   g_perm[NP];
__device__ int   g_nodemap[NTOTAL];
__device__ int   g_cnt[512];
__device__ int   g_off[512];
__device__ float g_norm;

// f32 -> bf16 RNE, returned as f32 (upper 16 bits kept). Ref is bf16-rounded.
__device__ __forceinline__ float bfr(float f){
  uint32_t u = __float_as_uint(f);
  uint32_t r = u + 0x7FFFu + ((u >> 16) & 1u);
  return __uint_as_float(r & 0xFFFF0000u);
}

// Bit-exact replication of XLA:CPU EmitTanh (f32). Verified passing in R2.
__device__ __forceinline__ float xla_tanhf(float x){
#pragma clang fp contract(off)
  float xc = fminf(fmaxf(x, -7.90531110763549805f), 7.90531110763549805f);
  float x2 = __fmul_rn(xc, xc);
  float p = -2.76076847742355e-16f;
  p = __fadd_rn(__fmul_rn(p, x2),  2.00018790482477e-13f);
  p = __fadd_rn(__fmul_rn(p, x2), -8.60467152213735e-11f);
  p = __fadd_rn(__fmul_rn(p, x2),  5.12229709037114e-08f);
  p = __fadd_rn(__fmul_rn(p, x2),  1.48572235717979e-05f);
  p = __fadd_rn(__fmul_rn(p, x2),  6.37261928875436e-04f);
  p = __fadd_rn(__fmul_rn(p, x2),  4.89352455891786e-03f);
  p = __fmul_rn(xc, p);
  float q = 1.19825839466702e-06f;
  q = __fadd_rn(__fmul_rn(q, x2), 1.18534705686654e-04f);
  q = __fadd_rn(__fmul_rn(q, x2), 2.26843463243900e-03f);
  q = __fadd_rn(__fmul_rn(q, x2), 4.89352518554385e-03f);
  float r = __fdiv_rn(p, q);
  return (fabsf(x) < 0.0004f) ? x : r;
}

// ||w||: one wave; lanes 0..15 replicate the exact 16-lane XLA chains,
// then the same shuffle-halving tree. Bit-identical to R2's serial version.
__global__ void k_norm(const float* __restrict__ w){
#pragma clang fp contract(off)
  int lane = threadIdx.x;
  float s = 0.f;
  if (lane < 16){
#pragma unroll
    for (int k = 0; k < 8; ++k){
      float t = w[k*16 + lane];
      s = __fadd_rn(s, __fmul_rn(t, t));
    }
  }
  float o;
  o = __shfl_down(s, 8); if (lane < 8) s = __fadd_rn(s, o);
  o = __shfl_down(s, 4); if (lane < 4) s = __fadd_rn(s, o);
  o = __shfl_down(s, 2); if (lane < 2) s = __fadd_rn(s, o);
  o = __shfl_down(s, 1);
  if (lane == 0) g_norm = __fsqrt_rn(__fadd_rn(s, o));
}

// score_i = xla_tanh( fdiv( dot16(x_i,w), norm ) ); also inits nodemap to -1.
__global__ __launch_bounds__(256) void k_scores(const float* __restrict__ x,
                                                const float* __restrict__ w){
#pragma clang fp contract(off)
  __shared__ float ws[NC];
  if (threadIdx.x < NC) ws[threadIdx.x] = w[threadIdx.x];
  __syncthreads();
  int i = blockIdx.x*256 + threadIdx.x;
  g_nodemap[i] = -1;                       // fused nm_init
  const float* row = x + (size_t)i*NC;
  float l[16];
#pragma unroll
  for (int j = 0; j < 16; ++j) l[j] = 0.f;
#pragma unroll
  for (int k = 0; k < NC; k += 16){
#pragma unroll
    for (int j = 0; j < 16; ++j)
      l[j] = __fadd_rn(l[j], __fmul_rn(row[k+j], ws[k+j]));
  }
#pragma unroll
  for (int j = 0; j < 8; ++j) l[j] = __fadd_rn(l[j], l[j+8]);
#pragma unroll
  for (int j = 0; j < 4; ++j) l[j] = __fadd_rn(l[j], l[j+4]);
#pragma unroll
  for (int j = 0; j < 2; ++j) l[j] = __fadd_rn(l[j], l[j+2]);
  float acc = __fadd_rn(l[0], l[1]);
  float t = __fdiv_rn(acc, g_norm);
  g_scores[i] = xla_tanhf(t);
}

// Sentence key: ascending u64 == (score descending, index ascending).
__device__ __forceinline__ unsigned long long skey(float s, int idx){
  uint32_t u = __float_as_uint(s);
  u = (u & 0x80000000u) ? ~u : (u | 0x80000000u);
  u = ~u;
  return ((unsigned long long)u << 32) | (uint32_t)idx;
}

// One block per graph. Sentence top-3 via 3 block-min extractions; other
// top-1792 via stable LSD radix sort (4 passes x 8-bit digits) on u32 key
// (descending-score map). Stability == index-ascending tie-break, matching
// the R2 bitonic's (score,index) total order. Also sets nodemap (fused).
__global__ __launch_bounds__(512) void k_topk(){
  __shared__ uint32_t keyA[NOTHER], keyB[NOTHER];
  __shared__ uint16_t idxA[NOTHER], idxB[NOTHER], rnk[NOTHER];
  __shared__ uint16_t cnt[8][256];   // per-wave digit counts -> wave offsets
  __shared__ uint16_t tot[256], dbase[256];
  __shared__ unsigned long long smin[8];
  __shared__ unsigned long long swin;

  int g = blockIdx.x, tid = threadIdx.x;
  int lane = tid & 63, wv = tid >> 6;
  const float* sg = g_scores + g*NN;

  // ---- sentence top-3 (512 nodes, one key per thread) ----
  unsigned long long key = skey(sg[tid], tid);
  for (int t = 0; t < KSENT; ++t){
    unsigned long long v = key;
#pragma unroll
    for (int off = 32; off; off >>= 1){
      unsigned long long o = __shfl_down(v, off);
      v = (o < v) ? o : v;
    }
    if (lane == 0) smin[wv] = v;
    __syncthreads();
    if (tid == 0){
      unsigned long long mm = smin[0];
      for (int w2 = 1; w2 < 8; ++w2) if (smin[w2] < mm) mm = smin[w2];
      swin = mm;
    }
    __syncthreads();
    unsigned long long winner = swin;
    if (key == winner){
      int idx = (int)(winner & 0xFFFFFFFFull);
      int node = g*NN + idx, p = g*KSENT + t;
      g_perm[p] = node;
      g_nodemap[node] = p;               // fused nm_set
      key = ~0ull;
    }
    __syncthreads();
  }

  // ---- others: load keys ----
  for (int i = tid; i < NOTHER; i += 512){
    uint32_t u = __float_as_uint(sg[NS + i]);
    u = (u & 0x80000000u) ? ~u : (u | 0x80000000u);
    keyA[i] = ~u;                        // ascending == score descending
    idxA[i] = (uint16_t)i;
  }
  __syncthreads();

  uint32_t* ksrc = keyA; uint32_t* kdst = keyB;
  uint16_t* isrc = idxA; uint16_t* idst = idxB;
  unsigned long long ltmask = (1ull << lane) - 1ull;
  int base = wv * 448;                   // 3584 = 8 waves * 448, 448 = 7*64

  for (int pass = 0; pass < 4; ++pass){
    int shift = pass * 8;
    // zero own wave's counters (no barrier needed: per-wave data)
    uint32_t* c32 = (uint32_t*)cnt[wv];
    c32[lane] = 0; c32[64 + lane] = 0;
    // rank: wave-chunked, rounds in source order -> stable
    for (int r = 0; r < 7; ++r){
      int i = base + r*64 + lane;
      uint32_t k = ksrc[i];
      uint32_t d = (k >> shift) & 255u;
      unsigned long long m = ~0ull;
#pragma unroll
      for (int b = 0; b < 8; ++b){
        unsigned long long bb = __ballot((d >> b) & 1u);
        m &= ((d >> b) & 1u) ? bb : ~bb;
      }
      int rir = __popcll(m & ltmask);
      uint16_t bse = cnt[wv][d];
      rnk[i] = (uint16_t)(bse + rir);
      if ((m >> lane) == 1ull)           // highest lane of digit group
        cnt[wv][d] = (uint16_t)(bse + __popcll(m));
    }
    __syncthreads();
    // scan: in-place exclusive over waves per digit, digit totals
    if (tid < 256){
      int s = 0;
#pragma unroll
      for (int w2 = 0; w2 < 8; ++w2){
        int t2 = cnt[w2][tid]; cnt[w2][tid] = (uint16_t)s; s += t2;
      }
      tot[tid] = (uint16_t)s;
    }
    __syncthreads();
    // exclusive scan of 256 digit totals (wave 0, 4 digits/lane)
    if (tid < 64){
      int b4 = tid*4;
      int s0=tot[b4], s1=tot[b4+1], s2=tot[b4+2], s3=tot[b4+3];
      int lsum = s0+s1+s2+s3;
      int sc = lsum;
      for (int off = 1; off < 64; off <<= 1){
        int vv = __shfl_up(sc, off);
        if (lane >= off) sc += vv;
      }
      int excl = sc - lsum;
      dbase[b4]   = (uint16_t)excl;
      dbase[b4+1] = (uint16_t)(excl + s0);
      dbase[b4+2] = (uint16_t)(excl + s0 + s1);
      dbase[b4+3] = (uint16_t)(excl + s0 + s1 + s2);
    }
    __syncthreads();
    // fold digit bases into wave offsets
    {
      int idx = tid;
#pragma unroll
      for (int kk = 0; kk < 4; ++kk){
        int w2 = (idx >> 8) & 7, d2 = idx & 255;
        cnt[w2][d2] = (uint16_t)(cnt[w2][d2] + dbase[d2]);
        idx += 512;
      }
    }
    __syncthreads();
    // scatter
    for (int r = 0; r < 7; ++r){
      int i = base + r*64 + lane;
      uint32_t k = ksrc[i];
      uint32_t d = (k >> shift) & 255u;
      int dest = cnt[wv][d] + rnk[i];
      kdst[dest] = k; idst[dest] = isrc[i];
    }
    __syncthreads();
    uint32_t* tk = ksrc; ksrc = kdst; kdst = tk;
    uint16_t* ti = isrc; isrc = idst; idst = ti;
  }
  // 4 passes -> result back in A (== isrc)
  for (int j = tid; j < KOTHER; j += 512){
    int node = g*NN + NS + (int)isrc[j];
    int p = NSENT_TOT + g*KOTHER + j;
    g_perm[p] = node;
    g_nodemap[node] = p;                 // fused nm_set
  }
}

// Per-block (8192 edges) kept-edge count + fused fill of edge region with -1.
__global__ __launch_bounds__(256) void k_count(const int* __restrict__ ei,
                                               float* __restrict__ out){
  int gt = blockIdx.x*256 + threadIdx.x;   // 131072 threads
  float4* f4 = (float4*)(out + OFF_EDGE);  // 2097152 float4s = 16 per thread
  float4 mv; mv.x = mv.y = mv.z = mv.w = -1.0f;
#pragma unroll
  for (int kk = 0; kk < 16; ++kk) f4[gt + kk*131072] = mv;

  int base = blockIdx.x * 8192;
  int c = 0;
  for (int s = 0; s < 8192; s += 256){
    int e = base + s + threadIdx.x;
    c += (g_nodemap[ei[e]] >= 0) && (g_nodemap[ei[NE + e]] >= 0);
  }
  __shared__ int red[256];
  red[threadIdx.x] = c; __syncthreads();
  for (int st = 128; st > 0; st >>= 1){
    if (threadIdx.x < st) red[threadIdx.x] += red[threadIdx.x + st];
    __syncthreads();
  }
  if (threadIdx.x == 0) g_cnt[blockIdx.x] = red[0];
}

// Exclusive scan of 512 block counts (one block, shuffle scan) + num_edges.
__global__ __launch_bounds__(512) void k_scan(float* __restrict__ out){
  __shared__ int wsums[8];
  int tid = threadIdx.x, lane = tid & 63, wv = tid >> 6;
  int c = g_cnt[tid];
  int sc = c;
  for (int off = 1; off < 64; off <<= 1){
    int v = __shfl_up(sc, off);
    if (lane >= off) sc += v;
  }
  if (lane == 63) wsums[wv] = sc;
  __syncthreads();
  int wb = 0;
  for (int w2 = 0; w2 < 8; ++w2) if (w2 < wv) wb += wsums[w2];
  g_off[tid] = wb + sc - c;
  if (tid == 511) out[OFF_NE] = bfr((float)(wb + sc));
}

// Stable compaction scatter: kept edges (remapped ids) to the front.
__global__ __launch_bounds__(256) void k_scatter(const int* __restrict__ ei,
                                                 float* __restrict__ out){
  __shared__ int wsum[4];
  int base = blockIdx.x * 8192;
  int running = g_off[blockIdx.x];
  int lane = threadIdx.x & 63, wid = threadIdx.x >> 6;
  for (int s = 0; s < 8192; s += 256){
    int e = base + s + threadIdx.x;
    int r = g_nodemap[ei[e]], c = g_nodemap[ei[NE + e]];
    bool keep = (r >= 0) && (c >= 0);
    unsigned long long m = __ballot(keep);
    if (lane == 0) wsum[wid] = __popcll(m);
    __syncthreads();
    int wbase = 0;
#pragma unroll
    for (int w2 = 0; w2 < 4; ++w2) if (w2 < wid) wbase += wsum[w2];
    int tot = wsum[0] + wsum[1] + wsum[2] + wsum[3];
    if (keep){
      int pos = running + wbase + __popcll(m & ((1ull << lane) - 1ull));
      out[OFF_EDGE + pos]      = bfr((float)r);
      out[OFF_EDGE + NE + pos] = bfr((float)c);
    }
    running += tot;
    __syncthreads();   // protect wsum from next iteration's overwrite
  }
}

// x_out = x[perm]*score[perm] (f32, bf16-rounded), float4-vectorized,
// plus batch/perm/score side outputs.
__global__ __launch_bounds__(256) void k_gather(const float* __restrict__ x,
                                                float* __restrict__ out){
  size_t q = (size_t)blockIdx.x*256 + threadIdx.x;   // NP*NC/4 threads
  int p  = (int)(q >> 5);          // 32 float4 per row
  int c4 = (int)(q & 31);
  int node = g_perm[p];
  float s = g_scores[node];
  float4 v = *(const float4*)(x + (size_t)node*NC + c4*4);
  float4 o;
  o.x = bfr(__fmul_rn(v.x, s));
  o.y = bfr(__fmul_rn(v.y, s));
  o.z = bfr(__fmul_rn(v.z, s));
  o.w = bfr(__fmul_rn(v.w, s));
  *(float4*)(out + OFF_X + (size_t)p*NC + c4*4) = o;
  if (c4 == 0){
    out[OFF_BATCH + p] = bfr((float)(node >> 12));
    out[OFF_PERM  + p] = bfr((float)node);
    out[OFF_SCORE + p] = bfr(s);
  }
}

extern "C" void kernel_launch(void* const* d_in, const int* in_sizes, int n_in,
                              void* d_out, int out_size, void* d_ws, size_t ws_size,
                              hipStream_t stream) {
  const float* x = (const float*)d_in[0];
  const float* w = (const float*)d_in[1];
  const int*   ei = (const int*)d_in[2];
  float* out = (float*)d_out;

  hipLaunchKernelGGL(k_norm,    dim3(1),              dim3(64),  0, stream, w);
  hipLaunchKernelGGL(k_scores,  dim3(NTOTAL/256),     dim3(256), 0, stream, x, w);
  hipLaunchKernelGGL(k_topk,    dim3(NB),             dim3(512), 0, stream);
  hipLaunchKernelGGL(k_count,   dim3(512),            dim3(256), 0, stream, ei, out);
  hipLaunchKernelGGL(k_scan,    dim3(1),              dim3(512), 0, stream, out);
  hipLaunchKernelGGL(k_scatter, dim3(512),            dim3(256), 0, stream, ei, out);
  hipLaunchKernelGGL(k_gather,  dim3((NP*NC/4)/256),  dim3(256), 0, stream, x, out);
}

// Round 4
// 119.959 us; speedup vs baseline: 2.0812x; 1.3127x over previous
//
#include <hip/hip_runtime.h>
#include <hip/hip_bf16.h>
#include <stdint.h>

// Problem constants (static graph layout)
#define NB 64
#define NN 4096
#define NS 512
#define NC 128
#define NTOTAL (NB*NN)          // 262144
#define NE 4194304
#define KSENT 3
#define KOTHER 1792
#define KPG (KSENT+KOTHER)      // 1795
#define NP (NB*KPG)             // 114880
#define NSENT_TOT (NB*KSENT)    // 192
#define NOTHER (NN-NS)          // 3584

// d_out element offsets (f32 elements), concatenated flat in return order:
// x_out[114880,128], edge_index_new[2,E], batch_out[P], perm[P], score[P], num_edges[1]
#define OFF_X     0ull
#define OFF_EDGE  14704640ull
#define OFF_BATCH 23093248ull
#define OFF_PERM  23208128ull
#define OFF_SCORE 23323008ull
#define OFF_NE    23437888ull

#define NEBLK 512               // edge-pipeline blocks
#define EPB   (NE/NEBLK)        // 8192 edges per block
#define STASH 4096              // LDS-stashed kept pairs per block (avg ~1575)

#define FLG_AGG (1ull<<62)
#define FLG_INC (2ull<<62)

// Module-scope scratch. ~2.5 MB total.
__device__ float g_scores[NTOTAL];
__device__ int   g_perm[NP];
__device__ int   g_nodemap[NTOTAL];
__device__ unsigned long long g_state[NEBLK];  // lookback: flag(2b)|value(32b)
__device__ int   g_total;

// f32 -> bf16 RNE, returned as f32 (upper 16 bits kept). Ref is bf16-rounded.
__device__ __forceinline__ float bfr(float f){
  uint32_t u = __float_as_uint(f);
  uint32_t r = u + 0x7FFFu + ((u >> 16) & 1u);
  return __uint_as_float(r & 0xFFFF0000u);
}

// Bit-exact replication of XLA:CPU EmitTanh (f32). Verified passing R2/R3.
__device__ __forceinline__ float xla_tanhf(float x){
#pragma clang fp contract(off)
  float xc = fminf(fmaxf(x, -7.90531110763549805f), 7.90531110763549805f);
  float x2 = __fmul_rn(xc, xc);
  float p = -2.76076847742355e-16f;
  p = __fadd_rn(__fmul_rn(p, x2),  2.00018790482477e-13f);
  p = __fadd_rn(__fmul_rn(p, x2), -8.60467152213735e-11f);
  p = __fadd_rn(__fmul_rn(p, x2),  5.12229709037114e-08f);
  p = __fadd_rn(__fmul_rn(p, x2),  1.48572235717979e-05f);
  p = __fadd_rn(__fmul_rn(p, x2),  6.37261928875436e-04f);
  p = __fadd_rn(__fmul_rn(p, x2),  4.89352455891786e-03f);
  p = __fmul_rn(xc, p);
  float q = 1.19825839466702e-06f;
  q = __fadd_rn(__fmul_rn(q, x2), 1.18534705686654e-04f);
  q = __fadd_rn(__fmul_rn(q, x2), 2.26843463243900e-03f);
  q = __fadd_rn(__fmul_rn(q, x2), 4.89352518554385e-03f);
  float r = __fdiv_rn(p, q);
  return (fabsf(x) < 0.0004f) ? x : r;
}

// Quarter-wave-per-row scores. Lane j of each 16-lane group owns the exact
// XLA vector-lane-j chain (elements 16k+j, k ascending, unfused mul+add),
// reduced by the identical shfl 8/4/2/1 tree -> bit-identical to R3 (passed).
// Memory: each wave instr reads 4 rows x 64 B contiguous segments (no L1
// thrash; every line fetched once). Also fuses nodemap init + g_state init.
__global__ __launch_bounds__(256) void k_scores(const float* __restrict__ x,
                                                const float* __restrict__ w){
#pragma clang fp contract(off)
  int tid = threadIdx.x;
  int gid = blockIdx.x*256 + tid;
  if (gid < NTOTAL) g_nodemap[gid] = -1;              // fused nm_init
  if (blockIdx.x == 0){ g_state[tid] = 0ull; g_state[256+tid] = 0ull; }

  int grp = tid >> 4, j = tid & 15;
  int row = blockIdx.x*16 + grp;
  const float* rx = x + (size_t)row*NC;

  float wv[8];
#pragma unroll
  for (int k = 0; k < 8; ++k) wv[k] = w[k*16 + j];

  // norm partial (lane-j chain), then dot partial (lane-j chain)
  float an = 0.f, ad = 0.f;
#pragma unroll
  for (int k = 0; k < 8; ++k) an = __fadd_rn(an, __fmul_rn(wv[k], wv[k]));
#pragma unroll
  for (int k = 0; k < 8; ++k) ad = __fadd_rn(ad, __fmul_rn(rx[k*16 + j], wv[k]));

  float o;
  o = __shfl_down(an, 8); if (j < 8) an = __fadd_rn(an, o);
  o = __shfl_down(ad, 8); if (j < 8) ad = __fadd_rn(ad, o);
  o = __shfl_down(an, 4); if (j < 4) an = __fadd_rn(an, o);
  o = __shfl_down(ad, 4); if (j < 4) ad = __fadd_rn(ad, o);
  o = __shfl_down(an, 2); if (j < 2) an = __fadd_rn(an, o);
  o = __shfl_down(ad, 2); if (j < 2) ad = __fadd_rn(ad, o);
  o = __shfl_down(an, 1);
  float o2 = __shfl_down(ad, 1);
  if (j == 0){
    float nrm = __fsqrt_rn(__fadd_rn(an, o));
    float acc = __fadd_rn(ad, o2);
    float t = __fdiv_rn(acc, nrm);
    g_scores[row] = xla_tanhf(t);
  }
}

// Sentence key: ascending u64 == (score descending, index ascending).
__device__ __forceinline__ unsigned long long skey(float s, int idx){
  uint32_t u = __float_as_uint(s);
  u = (u & 0x80000000u) ? ~u : (u | 0x80000000u);
  u = ~u;
  return ((unsigned long long)u << 32) | (uint32_t)idx;
}

// One block per graph: sentence top-3 via 3 block-min extractions; other
// top-1792 via stable LSD radix (4x8-bit) on u32 descending-score key.
// Stability == index-ascending tie-break. Sets nodemap (fused). (R3, passed.)
__global__ __launch_bounds__(512) void k_topk(){
  __shared__ uint32_t keyA[NOTHER], keyB[NOTHER];
  __shared__ uint16_t idxA[NOTHER], idxB[NOTHER], rnk[NOTHER];
  __shared__ uint16_t cnt[8][256];
  __shared__ uint16_t tot[256], dbase[256];
  __shared__ unsigned long long smin[8];
  __shared__ unsigned long long swin;

  int g = blockIdx.x, tid = threadIdx.x;
  int lane = tid & 63, wv = tid >> 6;
  const float* sg = g_scores + g*NN;

  unsigned long long key = skey(sg[tid], tid);
  for (int t = 0; t < KSENT; ++t){
    unsigned long long v = key;
#pragma unroll
    for (int off = 32; off; off >>= 1){
      unsigned long long o = __shfl_down(v, off);
      v = (o < v) ? o : v;
    }
    if (lane == 0) smin[wv] = v;
    __syncthreads();
    if (tid == 0){
      unsigned long long mm = smin[0];
      for (int w2 = 1; w2 < 8; ++w2) if (smin[w2] < mm) mm = smin[w2];
      swin = mm;
    }
    __syncthreads();
    unsigned long long winner = swin;
    if (key == winner){
      int idx = (int)(winner & 0xFFFFFFFFull);
      int node = g*NN + idx, p = g*KSENT + t;
      g_perm[p] = node;
      g_nodemap[node] = p;
      key = ~0ull;
    }
    __syncthreads();
  }

  for (int i = tid; i < NOTHER; i += 512){
    uint32_t u = __float_as_uint(sg[NS + i]);
    u = (u & 0x80000000u) ? ~u : (u | 0x80000000u);
    keyA[i] = ~u;
    idxA[i] = (uint16_t)i;
  }
  __syncthreads();

  uint32_t* ksrc = keyA; uint32_t* kdst = keyB;
  uint16_t* isrc = idxA; uint16_t* idst = idxB;
  unsigned long long ltmask = (1ull << lane) - 1ull;
  int base = wv * 448;

  for (int pass = 0; pass < 4; ++pass){
    int shift = pass * 8;
    uint32_t* c32 = (uint32_t*)cnt[wv];
    c32[lane] = 0; c32[64 + lane] = 0;
    for (int r = 0; r < 7; ++r){
      int i = base + r*64 + lane;
      uint32_t k = ksrc[i];
      uint32_t d = (k >> shift) & 255u;
      unsigned long long m = ~0ull;
#pragma unroll
      for (int b = 0; b < 8; ++b){
        unsigned long long bb = __ballot((d >> b) & 1u);
        m &= ((d >> b) & 1u) ? bb : ~bb;
      }
      int rir = __popcll(m & ltmask);
      uint16_t bse = cnt[wv][d];
      rnk[i] = (uint16_t)(bse + rir);
      if ((m >> lane) == 1ull)
        cnt[wv][d] = (uint16_t)(bse + __popcll(m));
    }
    __syncthreads();
    if (tid < 256){
      int s = 0;
#pragma unroll
      for (int w2 = 0; w2 < 8; ++w2){
        int t2 = cnt[w2][tid]; cnt[w2][tid] = (uint16_t)s; s += t2;
      }
      tot[tid] = (uint16_t)s;
    }
    __syncthreads();
    if (tid < 64){
      int b4 = tid*4;
      int s0=tot[b4], s1=tot[b4+1], s2=tot[b4+2], s3=tot[b4+3];
      int lsum = s0+s1+s2+s3;
      int sc = lsum;
      for (int off = 1; off < 64; off <<= 1){
        int vv = __shfl_up(sc, off);
        if (lane >= off) sc += vv;
      }
      int excl = sc - lsum;
      dbase[b4]   = (uint16_t)excl;
      dbase[b4+1] = (uint16_t)(excl + s0);
      dbase[b4+2] = (uint16_t)(excl + s0 + s1);
      dbase[b4+3] = (uint16_t)(excl + s0 + s1 + s2);
    }
    __syncthreads();
    {
      int idx = tid;
#pragma unroll
      for (int kk = 0; kk < 4; ++kk){
        int w2 = (idx >> 8) & 7, d2 = idx & 255;
        cnt[w2][d2] = (uint16_t)(cnt[w2][d2] + dbase[d2]);
        idx += 512;
      }
    }
    __syncthreads();
    for (int r = 0; r < 7; ++r){
      int i = base + r*64 + lane;
      uint32_t k = ksrc[i];
      uint32_t d = (k >> shift) & 255u;
      int dest = cnt[wv][d] + rnk[i];
      kdst[dest] = k; idst[dest] = isrc[i];
    }
    __syncthreads();
    uint32_t* tk = ksrc; ksrc = kdst; kdst = tk;
    uint16_t* ti = isrc; isrc = idst; idst = ti;
  }
  for (int j = tid; j < KOTHER; j += 512){
    int node = g*NN + NS + (int)isrc[j];
    int p = NSENT_TOT + g*KOTHER + j;
    g_perm[p] = node;
    g_nodemap[node] = p;
  }
}

// Single-pass stable edge compaction: per-block keep+stash (LDS), decoupled
// lookback for the global exclusive prefix, then write kept remapped edges.
// 512 blocks, 256 thr, 32 KB LDS -> far below co-residency capacity.
__global__ __launch_bounds__(256) void k_edges(const int* __restrict__ ei,
                                               float* __restrict__ out){
  __shared__ int2 rc[STASH];
  __shared__ int wsum[4];
  __shared__ int s_off;
  int b = blockIdx.x, tid = threadIdx.x;
  int lane = tid & 63, wid = tid >> 6;
  int base = b * EPB;
  unsigned long long ltm = (1ull << lane) - 1ull;

  // Phase A: keep flags, stable local positions, stash kept (r,c)
  int running = 0;
  for (int s = 0; s < EPB; s += 256){
    int e = base + s + tid;
    int r = g_nodemap[ei[e]], c = g_nodemap[ei[NE + e]];
    bool keep = (r >= 0) && (c >= 0);
    unsigned long long m = __ballot(keep);
    if (lane == 0) wsum[wid] = __popcll(m);
    __syncthreads();
    int wbase = 0;
#pragma unroll
    for (int w2 = 0; w2 < 4; ++w2) if (w2 < wid) wbase += wsum[w2];
    int tot = wsum[0] + wsum[1] + wsum[2] + wsum[3];
    if (keep){
      int lp = running + wbase + __popcll(m & ltm);
      if (lp < STASH){ int2 p; p.x = r; p.y = c; rc[lp] = p; }
    }
    running += tot;
    __syncthreads();
  }
  int myc = running;

  // Phase B: decoupled lookback (wave 0), device-scope packed atomics
  if (tid == 0) s_off = 0;
  if (b == 0){
    if (tid == 0){
      atomicExch(&g_state[0], FLG_INC | (unsigned long long)(uint32_t)myc);
    }
  } else if (wid == 0){
    if (lane == 0)
      atomicExch(&g_state[b], FLG_AGG | (unsigned long long)(uint32_t)myc);
    int prev = 0, win = b - 1;
    bool done = false;
    while (!done){
      int idxl = win - lane;
      unsigned long long st = (idxl >= 0) ? atomicAdd(&g_state[idxl], 0ull)
                                          : FLG_INC;  // virtual INC(0)
      unsigned f = (unsigned)(st >> 62);
      unsigned long long readym = __ballot(f != 0u);
      unsigned long long incm   = __ballot(f == 2u);
      if (incm){
        int l0 = __ffsll((long long)incm) - 1;   // closest INC predecessor
        unsigned long long needm = (l0 == 63) ? ~0ull : ((1ull << (l0+1)) - 1ull);
        if ((readym & needm) == needm){
          int contrib = (lane <= l0) ? (int)(uint32_t)st : 0;
#pragma unroll
          for (int off = 32; off; off >>= 1)
            contrib += __shfl_down(contrib, off);
          if (lane == 0) prev += contrib;
          done = true;
        }
      } else if (readym == ~0ull){
        int contrib = (int)(uint32_t)st;
#pragma unroll
        for (int off = 32; off; off >>= 1)
          contrib += __shfl_down(contrib, off);
        if (lane == 0) prev += contrib;
        win -= 64;
      } else {
        __builtin_amdgcn_s_sleep(2);
      }
    }
    if (lane == 0){
      atomicExch(&g_state[b], FLG_INC | (unsigned long long)(uint32_t)(prev + myc));
      s_off = prev;
      if (b == NEBLK-1){
        g_total = prev + myc;
        out[OFF_NE] = bfr((float)(prev + myc));
      }
    }
  }
  __syncthreads();
  if (b == NEBLK-1 && wid != 0){ /* g_total set by wave0 lane0 above */ }
  int off = s_off;
  if (b == 0 && tid == 0 && NEBLK == 1){ g_total = myc; }

  // Phase C: write kept edges from stash (coalesced)
  int lim = myc < STASH ? myc : STASH;
  for (int i = tid; i < lim; i += 256){
    int2 p = rc[i];
    out[OFF_EDGE + off + i]      = bfr((float)p.x);
    out[OFF_EDGE + NE + off + i] = bfr((float)p.y);
  }
  // Rare fallback: stash overflow -> recompute positions from global
  if (myc > STASH){
    running = 0;
    __syncthreads();
    for (int s = 0; s < EPB; s += 256){
      int e = base + s + tid;
      int r = g_nodemap[ei[e]], c = g_nodemap[ei[NE + e]];
      bool keep = (r >= 0) && (c >= 0);
      unsigned long long m = __ballot(keep);
      if (lane == 0) wsum[wid] = __popcll(m);
      __syncthreads();
      int wbase = 0;
#pragma unroll
      for (int w2 = 0; w2 < 4; ++w2) if (w2 < wid) wbase += wsum[w2];
      int tot = wsum[0] + wsum[1] + wsum[2] + wsum[3];
      if (keep){
        int lp = running + wbase + __popcll(m & ltm);
        if (lp >= STASH){
          out[OFF_EDGE + off + lp]      = bfr((float)r);
          out[OFF_EDGE + NE + off + lp] = bfr((float)c);
        }
      }
      running += tot;
      __syncthreads();
    }
  }
}

// Guarded tail fill: -1 into [T, NE) of both edge rows.
__global__ __launch_bounds__(256) void k_tail(float* __restrict__ out){
  int T = g_total;
  int i4 = blockIdx.x*256 + threadIdx.x;   // f4 index, NE/4 total
  int pos = i4 * 4;
  float4 mv; mv.x = mv.y = mv.z = mv.w = -1.0f;
  if (pos >= T){
    ((float4*)(out + OFF_EDGE))[i4] = mv;
    ((float4*)(out + OFF_EDGE + NE))[i4] = mv;
  } else if (pos + 4 > T){
    for (int k = T; k < pos + 4; ++k){
      out[OFF_EDGE + k] = -1.0f;
      out[OFF_EDGE + NE + k] = -1.0f;
    }
  }
}

// x_out = x[perm]*score[perm] (f32, bf16-rounded), float4-vectorized,
// plus batch/perm/score side outputs. (R3, passed.)
__global__ __launch_bounds__(256) void k_gather(const float* __restrict__ x,
                                                float* __restrict__ out){
  size_t q = (size_t)blockIdx.x*256 + threadIdx.x;   // NP*NC/4 threads
  int p  = (int)(q >> 5);
  int c4 = (int)(q & 31);
  int node = g_perm[p];
  float s = g_scores[node];
  float4 v = *(const float4*)(x + (size_t)node*NC + c4*4);
  float4 o;
  o.x = bfr(__fmul_rn(v.x, s));
  o.y = bfr(__fmul_rn(v.y, s));
  o.z = bfr(__fmul_rn(v.z, s));
  o.w = bfr(__fmul_rn(v.w, s));
  *(float4*)(out + OFF_X + (size_t)p*NC + c4*4) = o;
  if (c4 == 0){
    out[OFF_BATCH + p] = bfr((float)(node >> 12));
    out[OFF_PERM  + p] = bfr((float)node);
    out[OFF_SCORE + p] = bfr(s);
  }
}

extern "C" void kernel_launch(void* const* d_in, const int* in_sizes, int n_in,
                              void* d_out, int out_size, void* d_ws, size_t ws_size,
                              hipStream_t stream) {
  const float* x = (const float*)d_in[0];
  const float* w = (const float*)d_in[1];
  const int*   ei = (const int*)d_in[2];
  float* out = (float*)d_out;

  hipLaunchKernelGGL(k_scores, dim3(NTOTAL/16),      dim3(256), 0, stream, x, w);
  hipLaunchKernelGGL(k_topk,   dim3(NB),             dim3(512), 0, stream);
  hipLaunchKernelGGL(k_edges,  dim3(NEBLK),          dim3(256), 0, stream, ei, out);
  hipLaunchKernelGGL(k_tail,   dim3(NE/4/256),       dim3(256), 0, stream, out);
  hipLaunchKernelGGL(k_gather, dim3((NP*NC/4)/256),  dim3(256), 0, stream, x, out);
}

// Round 5
// 108.226 us; speedup vs baseline: 2.3068x; 1.1084x over previous
//
#include <hip/hip_runtime.h>
#include <hip/hip_bf16.h>
#include <stdint.h>

// Problem constants (static graph layout)
#define NB 64
#define NN 4096
#define NS 512
#define NC 128
#define NTOTAL (NB*NN)          // 262144
#define NE 4194304
#define KSENT 3
#define KOTHER 1792
#define KPG (KSENT+KOTHER)      // 1795
#define NP (NB*KPG)             // 114880
#define NSENT_TOT (NB*KSENT)    // 192
#define NOTHER (NN-NS)          // 3584

// d_out element offsets (f32 elements), concatenated flat in return order:
// x_out[114880,128], edge_index_new[2,E], batch_out[P], perm[P], score[P], num_edges[1]
#define OFF_X     0ull
#define OFF_EDGE  14704640ull
#define OFF_BATCH 23093248ull
#define OFF_PERM  23208128ull
#define OFF_SCORE 23323008ull
#define OFF_NE    23437888ull

#define NEBLK 512               // edge-pipeline blocks
#define EPB   (NE/NEBLK)        // 8192 edges per block
#define STASH 2560              // kept/block: mean 1575, sd 36 -> +27 sigma

#define NBW   (NTOTAL/32)       // 8192 bitmap words
#define GBLK  ((NP*NC/4)/256)   // 14360 gather blocks
#define TBLK  (NE/4/256)        // 4096 tail blocks

#define FLG_AGG (1ull<<62)
#define FLG_INC (2ull<<62)

// Module-scope scratch. ~2.5 MB total.
__device__ float g_scores[NTOTAL];
__device__ int   g_perm[NP];
__device__ int   g_nodemap[NTOTAL];
__device__ uint32_t g_bits[NBW];               // kept-node bitmap (== nodemap>=0)
__device__ unsigned long long g_state[NEBLK];  // lookback: flag(2b)|value(32b)
__device__ int   g_total;

// f32 -> bf16 RNE, returned as f32 (upper 16 bits kept). Ref is bf16-rounded.
__device__ __forceinline__ float bfr(float f){
  uint32_t u = __float_as_uint(f);
  uint32_t r = u + 0x7FFFu + ((u >> 16) & 1u);
  return __uint_as_float(r & 0xFFFF0000u);
}

// Bit-exact replication of XLA:CPU EmitTanh (f32). Verified passing R2-R4.
__device__ __forceinline__ float xla_tanhf(float x){
#pragma clang fp contract(off)
  float xc = fminf(fmaxf(x, -7.90531110763549805f), 7.90531110763549805f);
  float x2 = __fmul_rn(xc, xc);
  float p = -2.76076847742355e-16f;
  p = __fadd_rn(__fmul_rn(p, x2),  2.00018790482477e-13f);
  p = __fadd_rn(__fmul_rn(p, x2), -8.60467152213735e-11f);
  p = __fadd_rn(__fmul_rn(p, x2),  5.12229709037114e-08f);
  p = __fadd_rn(__fmul_rn(p, x2),  1.48572235717979e-05f);
  p = __fadd_rn(__fmul_rn(p, x2),  6.37261928875436e-04f);
  p = __fadd_rn(__fmul_rn(p, x2),  4.89352455891786e-03f);
  p = __fmul_rn(xc, p);
  float q = 1.19825839466702e-06f;
  q = __fadd_rn(__fmul_rn(q, x2), 1.18534705686654e-04f);
  q = __fadd_rn(__fmul_rn(q, x2), 2.26843463243900e-03f);
  q = __fadd_rn(__fmul_rn(q, x2), 4.89352518554385e-03f);
  float r = __fdiv_rn(p, q);
  return (fabsf(x) < 0.0004f) ? x : r;
}

// Quarter-wave-per-row scores; lane j owns the XLA vector-lane-j chain
// (elements 16k+j, k ascending, unfused mul+add), shfl 8/4/2/1 tree.
// Bit-identical to R3/R4 (passed). Fuses nodemap + lookback-state init.
__global__ __launch_bounds__(256) void k_scores(const float* __restrict__ x,
                                                const float* __restrict__ w){
#pragma clang fp contract(off)
  int tid = threadIdx.x;
  int gid = blockIdx.x*256 + tid;
  if (gid < NTOTAL) g_nodemap[gid] = -1;              // fused nm_init
  if (blockIdx.x == 0){ g_state[tid] = 0ull; g_state[256+tid] = 0ull; }

  int grp = tid >> 4, j = tid & 15;
  int row = blockIdx.x*16 + grp;
  const float* rx = x + (size_t)row*NC;

  float wv[8];
#pragma unroll
  for (int k = 0; k < 8; ++k) wv[k] = w[k*16 + j];

  float an = 0.f, ad = 0.f;
#pragma unroll
  for (int k = 0; k < 8; ++k) an = __fadd_rn(an, __fmul_rn(wv[k], wv[k]));
#pragma unroll
  for (int k = 0; k < 8; ++k) ad = __fadd_rn(ad, __fmul_rn(rx[k*16 + j], wv[k]));

  float o;
  o = __shfl_down(an, 8); if (j < 8) an = __fadd_rn(an, o);
  o = __shfl_down(ad, 8); if (j < 8) ad = __fadd_rn(ad, o);
  o = __shfl_down(an, 4); if (j < 4) an = __fadd_rn(an, o);
  o = __shfl_down(ad, 4); if (j < 4) ad = __fadd_rn(ad, o);
  o = __shfl_down(an, 2); if (j < 2) an = __fadd_rn(an, o);
  o = __shfl_down(ad, 2); if (j < 2) ad = __fadd_rn(ad, o);
  o = __shfl_down(an, 1);
  float o2 = __shfl_down(ad, 1);
  if (j == 0){
    float nrm = __fsqrt_rn(__fadd_rn(an, o));
    float acc = __fadd_rn(ad, o2);
    float t = __fdiv_rn(acc, nrm);
    g_scores[row] = xla_tanhf(t);
  }
}

// Sentence key: ascending u64 == (score descending, index ascending).
__device__ __forceinline__ unsigned long long skey(float s, int idx){
  uint32_t u = __float_as_uint(s);
  u = (u & 0x80000000u) ? ~u : (u | 0x80000000u);
  u = ~u;
  return ((unsigned long long)u << 32) | (uint32_t)idx;
}

// One block per graph: sentence top-3 via 3 block-min extractions; other
// top-1792 via stable LSD radix (4x8-bit). Sets nodemap + kept-bitmap words
// for its own graph (128 words, built in LDS -> no global atomics).
__global__ __launch_bounds__(512) void k_topk(){
  __shared__ uint32_t keyA[NOTHER], keyB[NOTHER];
  __shared__ uint16_t idxA[NOTHER], idxB[NOTHER], rnk[NOTHER];
  __shared__ uint16_t cnt[8][256];
  __shared__ uint16_t tot[256], dbase[256];
  __shared__ unsigned long long smin[8];
  __shared__ unsigned long long swin;
  __shared__ uint32_t bl[NN/32];   // 128 words: this graph's kept bitmap

  int g = blockIdx.x, tid = threadIdx.x;
  int lane = tid & 63, wv = tid >> 6;
  const float* sg = g_scores + g*NN;

  if (tid < NN/32) bl[tid] = 0u;
  __syncthreads();

  unsigned long long key = skey(sg[tid], tid);
  for (int t = 0; t < KSENT; ++t){
    unsigned long long v = key;
#pragma unroll
    for (int off = 32; off; off >>= 1){
      unsigned long long o = __shfl_down(v, off);
      v = (o < v) ? o : v;
    }
    if (lane == 0) smin[wv] = v;
    __syncthreads();
    if (tid == 0){
      unsigned long long mm = smin[0];
      for (int w2 = 1; w2 < 8; ++w2) if (smin[w2] < mm) mm = smin[w2];
      swin = mm;
    }
    __syncthreads();
    unsigned long long winner = swin;
    if (key == winner){
      int idx = (int)(winner & 0xFFFFFFFFull);
      int node = g*NN + idx, p = g*KSENT + t;
      g_perm[p] = node;
      g_nodemap[node] = p;
      atomicOr(&bl[idx >> 5], 1u << (idx & 31));
      key = ~0ull;
    }
    __syncthreads();
  }

  for (int i = tid; i < NOTHER; i += 512){
    uint32_t u = __float_as_uint(sg[NS + i]);
    u = (u & 0x80000000u) ? ~u : (u | 0x80000000u);
    keyA[i] = ~u;
    idxA[i] = (uint16_t)i;
  }
  __syncthreads();

  uint32_t* ksrc = keyA; uint32_t* kdst = keyB;
  uint16_t* isrc = idxA; uint16_t* idst = idxB;
  unsigned long long ltmask = (1ull << lane) - 1ull;
  int base = wv * 448;

  for (int pass = 0; pass < 4; ++pass){
    int shift = pass * 8;
    uint32_t* c32 = (uint32_t*)cnt[wv];
    c32[lane] = 0; c32[64 + lane] = 0;
    for (int r = 0; r < 7; ++r){
      int i = base + r*64 + lane;
      uint32_t k = ksrc[i];
      uint32_t d = (k >> shift) & 255u;
      unsigned long long m = ~0ull;
#pragma unroll
      for (int b = 0; b < 8; ++b){
        unsigned long long bb = __ballot((d >> b) & 1u);
        m &= ((d >> b) & 1u) ? bb : ~bb;
      }
      int rir = __popcll(m & ltmask);
      uint16_t bse = cnt[wv][d];
      rnk[i] = (uint16_t)(bse + rir);
      if ((m >> lane) == 1ull)
        cnt[wv][d] = (uint16_t)(bse + __popcll(m));
    }
    __syncthreads();
    if (tid < 256){
      int s = 0;
#pragma unroll
      for (int w2 = 0; w2 < 8; ++w2){
        int t2 = cnt[w2][tid]; cnt[w2][tid] = (uint16_t)s; s += t2;
      }
      tot[tid] = (uint16_t)s;
    }
    __syncthreads();
    if (tid < 64){
      int b4 = tid*4;
      int s0=tot[b4], s1=tot[b4+1], s2=tot[b4+2], s3=tot[b4+3];
      int lsum = s0+s1+s2+s3;
      int sc = lsum;
      for (int off = 1; off < 64; off <<= 1){
        int vv = __shfl_up(sc, off);
        if (lane >= off) sc += vv;
      }
      int excl = sc - lsum;
      dbase[b4]   = (uint16_t)excl;
      dbase[b4+1] = (uint16_t)(excl + s0);
      dbase[b4+2] = (uint16_t)(excl + s0 + s1);
      dbase[b4+3] = (uint16_t)(excl + s0 + s1 + s2);
    }
    __syncthreads();
    {
      int idx = tid;
#pragma unroll
      for (int kk = 0; kk < 4; ++kk){
        int w2 = (idx >> 8) & 7, d2 = idx & 255;
        cnt[w2][d2] = (uint16_t)(cnt[w2][d2] + dbase[d2]);
        idx += 512;
      }
    }
    __syncthreads();
    for (int r = 0; r < 7; ++r){
      int i = base + r*64 + lane;
      uint32_t k = ksrc[i];
      uint32_t d = (k >> shift) & 255u;
      int dest = cnt[wv][d] + rnk[i];
      kdst[dest] = k; idst[dest] = isrc[i];
    }
    __syncthreads();
    uint32_t* tk = ksrc; ksrc = kdst; kdst = tk;
    uint16_t* ti = isrc; isrc = idst; idst = ti;
  }
  for (int j = tid; j < KOTHER; j += 512){
    int li = NS + (int)isrc[j];
    int node = g*NN + li;
    int p = NSENT_TOT + g*KOTHER + j;
    g_perm[p] = node;
    g_nodemap[node] = p;
    atomicOr(&bl[li >> 5], 1u << (li & 31));
  }
  __syncthreads();
  if (tid < NN/32) g_bits[g*(NN/32) + tid] = bl[tid];
}

// Single-pass stable edge compaction. Keep test via 32KB LDS bitmap (cheap,
// no L2 scatter); nodemap values read only for kept edges (~19%).
__global__ __launch_bounds__(256) void k_edges(const int* __restrict__ ei,
                                               float* __restrict__ out){
  __shared__ uint32_t bm[NBW];    // 32 KB
  __shared__ int2 rc[STASH];      // 20 KB
  __shared__ int wsum[4];
  __shared__ int s_off;
  int b = blockIdx.x, tid = threadIdx.x;
  int lane = tid & 63, wid = tid >> 6;
  int base = b * EPB;
  unsigned long long ltm = (1ull << lane) - 1ull;

  // stage bitmap (8192 words / 256 thr = 8 x dwordx4)
  {
    uint4* d4 = (uint4*)bm;
    const uint4* s4 = (const uint4*)g_bits;
#pragma unroll
    for (int kk = 0; kk < 8; ++kk) d4[tid + kk*256] = s4[tid + kk*256];
  }
  if (tid == 0) s_off = 0;
  __syncthreads();

  // Phase A: keep flags from LDS bitmap, stable local positions, stash
  int running = 0;
  for (int s = 0; s < EPB; s += 256){
    int e = base + s + tid;
    int u = ei[e], v = ei[NE + e];
    bool keep = ((bm[u >> 5] >> (u & 31)) & 1u) &&
                ((bm[v >> 5] >> (v & 31)) & 1u);
    unsigned long long m = __ballot(keep);
    if (lane == 0) wsum[wid] = __popcll(m);
    __syncthreads();
    int wbase = 0;
#pragma unroll
    for (int w2 = 0; w2 < 4; ++w2) if (w2 < wid) wbase += wsum[w2];
    int tot = wsum[0] + wsum[1] + wsum[2] + wsum[3];
    if (keep){
      int lp = running + wbase + __popcll(m & ltm);
      if (lp < STASH){
        int2 p; p.x = g_nodemap[u]; p.y = g_nodemap[v]; rc[lp] = p;
      }
    }
    running += tot;
    __syncthreads();
  }
  int myc = running;

  // Phase B: decoupled lookback (wave 0)
  if (b == 0){
    if (tid == 0)
      atomicExch(&g_state[0], FLG_INC | (unsigned long long)(uint32_t)myc);
  } else if (wid == 0){
    if (lane == 0)
      atomicExch(&g_state[b], FLG_AGG | (unsigned long long)(uint32_t)myc);
    int prev = 0, win = b - 1;
    bool done = false;
    while (!done){
      int idxl = win - lane;
      unsigned long long st = (idxl >= 0) ? atomicAdd(&g_state[idxl], 0ull)
                                          : FLG_INC;
      unsigned f = (unsigned)(st >> 62);
      unsigned long long readym = __ballot(f != 0u);
      unsigned long long incm   = __ballot(f == 2u);
      if (incm){
        int l0 = __ffsll((long long)incm) - 1;
        unsigned long long needm = (l0 == 63) ? ~0ull : ((1ull << (l0+1)) - 1ull);
        if ((readym & needm) == needm){
          int contrib = (lane <= l0) ? (int)(uint32_t)st : 0;
#pragma unroll
          for (int off = 32; off; off >>= 1)
            contrib += __shfl_down(contrib, off);
          if (lane == 0) prev += contrib;
          done = true;
        }
      } else if (readym == ~0ull){
        int contrib = (int)(uint32_t)st;
#pragma unroll
        for (int off = 32; off; off >>= 1)
          contrib += __shfl_down(contrib, off);
        if (lane == 0) prev += contrib;
        win -= 64;
      } else {
        __builtin_amdgcn_s_sleep(2);
      }
    }
    if (lane == 0){
      atomicExch(&g_state[b], FLG_INC | (unsigned long long)(uint32_t)(prev + myc));
      s_off = prev;
      if (b == NEBLK-1){
        g_total = prev + myc;
        out[OFF_NE] = bfr((float)(prev + myc));
      }
    }
  }
  __syncthreads();
  int off = s_off;

  // Phase C: write kept edges from stash (coalesced)
  int lim = myc < STASH ? myc : STASH;
  for (int i = tid; i < lim; i += 256){
    int2 p = rc[i];
    out[OFF_EDGE + off + i]      = bfr((float)p.x);
    out[OFF_EDGE + NE + off + i] = bfr((float)p.y);
  }
  // Rare fallback: stash overflow -> recompute positions
  if (myc > STASH){
    running = 0;
    __syncthreads();
    for (int s = 0; s < EPB; s += 256){
      int e = base + s + tid;
      int u = ei[e], v = ei[NE + e];
      bool keep = ((bm[u >> 5] >> (u & 31)) & 1u) &&
                  ((bm[v >> 5] >> (v & 31)) & 1u);
      unsigned long long m = __ballot(keep);
      if (lane == 0) wsum[wid] = __popcll(m);
      __syncthreads();
      int wbase = 0;
#pragma unroll
      for (int w2 = 0; w2 < 4; ++w2) if (w2 < wid) wbase += wsum[w2];
      int tot = wsum[0] + wsum[1] + wsum[2] + wsum[3];
      if (keep){
        int lp = running + wbase + __popcll(m & ltm);
        if (lp >= STASH){
          out[OFF_EDGE + off + lp]      = bfr((float)g_nodemap[u]);
          out[OFF_EDGE + NE + off + lp] = bfr((float)g_nodemap[v]);
        }
      }
      running += tot;
      __syncthreads();
    }
  }
}

// Fused gather + tail-fill (blockIdx-partitioned).
__global__ __launch_bounds__(256) void k_gather(const float* __restrict__ x,
                                                float* __restrict__ out){
  if (blockIdx.x < GBLK){
    size_t q = (size_t)blockIdx.x*256 + threadIdx.x;
    int p  = (int)(q >> 5);
    int c4 = (int)(q & 31);
    int node = g_perm[p];
    float s = g_scores[node];
    float4 v = *(const float4*)(x + (size_t)node*NC + c4*4);
    float4 o;
    o.x = bfr(__fmul_rn(v.x, s));
    o.y = bfr(__fmul_rn(v.y, s));
    o.z = bfr(__fmul_rn(v.z, s));
    o.w = bfr(__fmul_rn(v.w, s));
    *(float4*)(out + OFF_X + (size_t)p*NC + c4*4) = o;
    if (c4 == 0){
      out[OFF_BATCH + p] = bfr((float)(node >> 12));
      out[OFF_PERM  + p] = bfr((float)node);
      out[OFF_SCORE + p] = bfr(s);
    }
  } else {
    int T = g_total;
    int i4 = (blockIdx.x - GBLK)*256 + threadIdx.x;
    int pos = i4 * 4;
    float4 mv; mv.x = mv.y = mv.z = mv.w = -1.0f;
    if (pos >= T){
      ((float4*)(out + OFF_EDGE))[i4] = mv;
      ((float4*)(out + OFF_EDGE + NE))[i4] = mv;
    } else if (pos + 4 > T){
      for (int k = T; k < pos + 4; ++k){
        out[OFF_EDGE + k] = -1.0f;
        out[OFF_EDGE + NE + k] = -1.0f;
      }
    }
  }
}

extern "C" void kernel_launch(void* const* d_in, const int* in_sizes, int n_in,
                              void* d_out, int out_size, void* d_ws, size_t ws_size,
                              hipStream_t stream) {
  const float* x = (const float*)d_in[0];
  const float* w = (const float*)d_in[1];
  const int*   ei = (const int*)d_in[2];
  float* out = (float*)d_out;

  hipLaunchKernelGGL(k_scores, dim3(NTOTAL/16),    dim3(256), 0, stream, x, w);
  hipLaunchKernelGGL(k_topk,   dim3(NB),           dim3(512), 0, stream);
  hipLaunchKernelGGL(k_edges,  dim3(NEBLK),        dim3(256), 0, stream, ei, out);
  hipLaunchKernelGGL(k_gather, dim3(GBLK + TBLK),  dim3(256), 0, stream, x, out);
}